// Round 1
// baseline (495.675 us; speedup 1.0000x reference)
//
#include <hip/hip_runtime.h>
#include <hip/hip_bf16.h>
#include <math.h>

#define SET_SIZE 8
#define EMB_DIM 64
#define NPAIR 36  // upper triangle incl diagonal of 8x8

__global__ __launch_bounds__(256) void hyperedge_score_kernel(
    const float* __restrict__ node_emb,       // [N_NODES, 64]
    const float* __restrict__ hyperedge_emb,  // [N_HYPEREDGES, 64]
    const int*   __restrict__ h,              // [E]
    const int*   __restrict__ X,              // [E, 8]
    float*       __restrict__ out,            // [E, 2]
    int n_cand)
{
    int e = blockIdx.x * blockDim.x + threadIdx.x;
    if (e >= n_cand) return;

    // Gather row pointers
    const float4* src = (const float4*)(hyperedge_emb + (size_t)h[e] * EMB_DIM);

    // Coalesced load of the 8 node indices (two int4 = 32B, aligned)
    const int4* Xv = (const int4*)(X + (size_t)e * SET_SIZE);
    int4 x0 = Xv[0];
    int4 x1 = Xv[1];
    int xi[SET_SIZE] = {x0.x, x0.y, x0.z, x0.w, x1.x, x1.y, x1.z, x1.w};

    const float4* nptr[SET_SIZE];
#pragma unroll
    for (int s = 0; s < SET_SIZE; ++s)
        nptr[s] = (const float4*)(node_emb + (size_t)xi[s] * EMB_DIM);

    float star[SET_SIZE];
    float pair[NPAIR];
#pragma unroll
    for (int s = 0; s < SET_SIZE; ++s) star[s] = 0.f;
#pragma unroll
    for (int k = 0; k < NPAIR; ++k) pair[k] = 0.f;

    // Stream the 64-dim embeddings in float4 chunks (16 iterations)
#pragma unroll 4
    for (int c = 0; c < EMB_DIM / 4; ++c) {
        float4 a = src[c];
        float4 v[SET_SIZE];
#pragma unroll
        for (int s = 0; s < SET_SIZE; ++s) v[s] = nptr[s][c];

#pragma unroll
        for (int s = 0; s < SET_SIZE; ++s) {
            star[s] = fmaf(a.x, v[s].x,
                      fmaf(a.y, v[s].y,
                      fmaf(a.z, v[s].z,
                      fmaf(a.w, v[s].w, star[s]))));
        }
        int k = 0;
#pragma unroll
        for (int s = 0; s < SET_SIZE; ++s) {
#pragma unroll
            for (int t = s; t < SET_SIZE; ++t, ++k) {
                pair[k] = fmaf(v[s].x, v[t].x,
                          fmaf(v[s].y, v[t].y,
                          fmaf(v[s].z, v[t].z,
                          fmaf(v[s].w, v[t].w, pair[k]))));
            }
        }
    }

    // min over raw dots; sigmoid is monotonic so sigmoid(min) == min(sigmoid)
    float smin = star[0];
#pragma unroll
    for (int s = 1; s < SET_SIZE; ++s) smin = fminf(smin, star[s]);
    float pmin = pair[0];
#pragma unroll
    for (int k = 1; k < NPAIR; ++k) pmin = fminf(pmin, pair[k]);

    float star_sig   = 1.0f / (1.0f + __expf(-smin));
    float clique_sig = 1.0f / (1.0f + __expf(-pmin));

    out[(size_t)e * 2 + 0] = star_sig;
    out[(size_t)e * 2 + 1] = clique_sig;
}

extern "C" void kernel_launch(void* const* d_in, const int* in_sizes, int n_in,
                              void* d_out, int out_size, void* d_ws, size_t ws_size,
                              hipStream_t stream) {
    const float* node_emb      = (const float*)d_in[0];
    const float* hyperedge_emb = (const float*)d_in[1];
    const int*   h             = (const int*)d_in[2];
    const int*   X             = (const int*)d_in[3];
    float*       out           = (float*)d_out;

    int n_cand = in_sizes[2];  // h has one entry per candidate

    int block = 256;
    int grid = (n_cand + block - 1) / block;
    hyperedge_score_kernel<<<grid, block, 0, stream>>>(
        node_emb, hyperedge_emb, h, X, out, n_cand);
}

// Round 2
// 134.189 us; speedup vs baseline: 3.6939x; 3.6939x over previous
//
#include <hip/hip_runtime.h>
#include <math.h>

#define SET_SIZE 8
#define EMB_DIM 64
#define NPAIR 36  // upper triangle incl diagonal of 8x8
#define NDOT (SET_SIZE + NPAIR)

__device__ __forceinline__ float dot4(float4 a, float4 b) {
    return fmaf(a.x, b.x, fmaf(a.y, b.y, fmaf(a.z, b.z, a.w * b.w)));
}

// 8 lanes per candidate. Each lane holds 8 consecutive floats (2x float4) of
// each of the 9 gathered rows -> every row load is a fully-coalesced,
// fully-used 256B segment (8 lanes x 32B). Dot products accumulate per-lane,
// then a 3-step shfl_xor reduction finishes each of the 44 dots.
__global__ __launch_bounds__(256) void hyperedge_score_g8(
    const float* __restrict__ node_emb,       // [N_NODES, 64]
    const float* __restrict__ hyperedge_emb,  // [N_HYPEREDGES, 64]
    const int*   __restrict__ h,              // [E]
    const int*   __restrict__ X,              // [E, 8]
    float*       __restrict__ out,            // [E, 2]
    int n_cand)
{
    int tid = blockIdx.x * blockDim.x + threadIdx.x;
    int grp = tid >> 3;   // candidate id
    int q   = tid & 7;    // lane within 8-lane group
    if (grp >= n_cand) return;

    // All 8 lanes of a group read the same 32B X row / 4B h -> broadcast.
    const int4* Xv = (const int4*)(X + (size_t)grp * SET_SIZE);
    int4 x0 = Xv[0];
    int4 x1 = Xv[1];
    int he = h[grp];
    int idx[SET_SIZE] = {x0.x, x0.y, x0.z, x0.w, x1.x, x1.y, x1.z, x1.w};

    // Row fragments: lane q owns floats [8q, 8q+8) of each row.
    float4 va[9], vb[9];
#pragma unroll
    for (int r = 0; r < SET_SIZE; ++r) {
        const float4* p = (const float4*)(node_emb + (size_t)idx[r] * EMB_DIM) + 2 * q;
        va[r] = p[0];
        vb[r] = p[1];
    }
    {
        const float4* p = (const float4*)(hyperedge_emb + (size_t)he * EMB_DIM) + 2 * q;
        va[8] = p[0];
        vb[8] = p[1];
    }

    // Per-lane partial dots: 8 star + 36 pair (upper triangle incl diagonal).
    float acc[NDOT];
#pragma unroll
    for (int s = 0; s < SET_SIZE; ++s)
        acc[s] = dot4(va[8], va[s]) + dot4(vb[8], vb[s]);
    {
        int k = SET_SIZE;
#pragma unroll
        for (int s = 0; s < SET_SIZE; ++s) {
#pragma unroll
            for (int t = s; t < SET_SIZE; ++t, ++k)
                acc[k] = dot4(va[s], va[t]) + dot4(vb[s], vb[t]);
        }
    }

    // Butterfly-reduce each dot across the 8-lane group (masks < 8 stay in-group).
#pragma unroll
    for (int i = 0; i < NDOT; ++i) {
        float x = acc[i];
        x += __shfl_xor(x, 1);
        x += __shfl_xor(x, 2);
        x += __shfl_xor(x, 4);
        acc[i] = x;
    }

    // sigmoid is monotonic: min(sigmoid(x)) == sigmoid(min(x))
    float smin = acc[0];
#pragma unroll
    for (int s = 1; s < SET_SIZE; ++s) smin = fminf(smin, acc[s]);
    float pmin = acc[SET_SIZE];
#pragma unroll
    for (int i = 1; i < NPAIR; ++i) pmin = fminf(pmin, acc[SET_SIZE + i]);

    float res = (q == 0) ? 1.0f / (1.0f + __expf(-smin))
                         : 1.0f / (1.0f + __expf(-pmin));
    if (q < 2) out[(size_t)grp * 2 + q] = res;
}

extern "C" void kernel_launch(void* const* d_in, const int* in_sizes, int n_in,
                              void* d_out, int out_size, void* d_ws, size_t ws_size,
                              hipStream_t stream) {
    const float* node_emb      = (const float*)d_in[0];
    const float* hyperedge_emb = (const float*)d_in[1];
    const int*   h             = (const int*)d_in[2];
    const int*   X             = (const int*)d_in[3];
    float*       out           = (float*)d_out;

    int n_cand = in_sizes[2];  // h has one entry per candidate

    int block = 256;
    long long total_threads = (long long)n_cand * 8;
    int grid = (int)((total_threads + block - 1) / block);
    hyperedge_score_g8<<<grid, block, 0, stream>>>(
        node_emb, hyperedge_emb, h, X, out, n_cand);
}

// Round 3
// 125.567 us; speedup vs baseline: 3.9475x; 1.0687x over previous
//
#include <hip/hip_runtime.h>
#include <hip/hip_fp16.h>
#include <math.h>

#define SET_SIZE 8
#define EMB_DIM 64
#define NPAIR 36  // upper triangle incl diagonal of 8x8
#define NDOT (SET_SIZE + NPAIR)

typedef _Float16 f16x2 __attribute__((ext_vector_type(2)));

union Frag16 {
    float4 f4;     // 16B raw load
    f16x2  h2[4];  // 8 fp16 elements
};

__device__ __forceinline__ float dot8_f16(const Frag16& a, const Frag16& b, float c) {
#if __has_builtin(__builtin_amdgcn_fdot2)
    c = __builtin_amdgcn_fdot2(a.h2[0], b.h2[0], c, false);
    c = __builtin_amdgcn_fdot2(a.h2[1], b.h2[1], c, false);
    c = __builtin_amdgcn_fdot2(a.h2[2], b.h2[2], c, false);
    c = __builtin_amdgcn_fdot2(a.h2[3], b.h2[3], c, false);
#else
#pragma unroll
    for (int j = 0; j < 4; ++j) {
        c = fmaf((float)a.h2[j].x, (float)b.h2[j].x, c);
        c = fmaf((float)a.h2[j].y, (float)b.h2[j].y, c);
    }
#endif
    return c;
}

// f32 -> f16 conversion, 8 floats per thread (two float4 reads, one 16B write)
__global__ __launch_bounds__(256) void cvt_f32_f16_kernel(
    const float* __restrict__ in, __half* __restrict__ out, int n8)
{
    int i = blockIdx.x * blockDim.x + threadIdx.x;
    if (i >= n8) return;
    const float4* p = (const float4*)in + 2 * (size_t)i;
    float4 a = p[0], b = p[1];
    union { __half2 h2[4]; float4 f4; } u;
    u.h2[0] = __floats2half2_rn(a.x, a.y);
    u.h2[1] = __floats2half2_rn(a.z, a.w);
    u.h2[2] = __floats2half2_rn(b.x, b.y);
    u.h2[3] = __floats2half2_rn(b.z, b.w);
    ((float4*)out)[i] = u.f4;
}

// 8 lanes per candidate; each lane holds 8 consecutive fp16 elems (16B, one
// dwordx4) of each of the 9 gathered rows -> one fully-used 128B segment per
// row gather. 44 dots accumulate per-lane in f32 via v_dot2_f32_f16, then a
// 3-step shfl_xor butterfly finishes each dot across the 8-lane group.
__global__ __launch_bounds__(256) void hyperedge_score_f16(
    const __half* __restrict__ node_f16,   // [N_NODES, 64]
    const __half* __restrict__ he_f16,     // [N_HYPEREDGES, 64]
    const int*    __restrict__ h,          // [E]
    const int*    __restrict__ X,          // [E, 8]
    float*        __restrict__ out,        // [E, 2]
    int n_cand)
{
    int tid = blockIdx.x * blockDim.x + threadIdx.x;
    int grp = tid >> 3;   // candidate id
    int q   = tid & 7;    // lane within 8-lane group
    if (grp >= n_cand) return;

    const int4* Xv = (const int4*)(X + (size_t)grp * SET_SIZE);
    int4 x0 = Xv[0];
    int4 x1 = Xv[1];
    int he = h[grp];
    int idx[SET_SIZE] = {x0.x, x0.y, x0.z, x0.w, x1.x, x1.y, x1.z, x1.w};

    Frag16 v[9];
#pragma unroll
    for (int r = 0; r < SET_SIZE; ++r)
        v[r].f4 = *((const float4*)(node_f16 + (size_t)idx[r] * EMB_DIM) + q);
    v[8].f4 = *((const float4*)(he_f16 + (size_t)he * EMB_DIM) + q);

    float acc[NDOT];
#pragma unroll
    for (int s = 0; s < SET_SIZE; ++s)
        acc[s] = dot8_f16(v[8], v[s], 0.0f);
    {
        int k = SET_SIZE;
#pragma unroll
        for (int s = 0; s < SET_SIZE; ++s) {
#pragma unroll
            for (int t = s; t < SET_SIZE; ++t, ++k)
                acc[k] = dot8_f16(v[s], v[t], 0.0f);
        }
    }

    // Butterfly-reduce each dot across the 8-lane group.
#pragma unroll
    for (int i = 0; i < NDOT; ++i) {
        float x = acc[i];
        x += __shfl_xor(x, 1);
        x += __shfl_xor(x, 2);
        x += __shfl_xor(x, 4);
        acc[i] = x;
    }

    // sigmoid is monotonic: min(sigmoid(x)) == sigmoid(min(x))
    float smin = acc[0];
#pragma unroll
    for (int s = 1; s < SET_SIZE; ++s) smin = fminf(smin, acc[s]);
    float pmin = acc[SET_SIZE];
#pragma unroll
    for (int i = 1; i < NPAIR; ++i) pmin = fminf(pmin, acc[SET_SIZE + i]);

    float res = (q == 0) ? 1.0f / (1.0f + __expf(-smin))
                         : 1.0f / (1.0f + __expf(-pmin));
    if (q < 2) out[(size_t)grp * 2 + q] = res;
}

// ---- f32 fallback (identical to R2) if workspace is too small ----
__device__ __forceinline__ float dot4f(float4 a, float4 b) {
    return fmaf(a.x, b.x, fmaf(a.y, b.y, fmaf(a.z, b.z, a.w * b.w)));
}

__global__ __launch_bounds__(256) void hyperedge_score_f32(
    const float* __restrict__ node_emb, const float* __restrict__ hyperedge_emb,
    const int* __restrict__ h, const int* __restrict__ X,
    float* __restrict__ out, int n_cand)
{
    int tid = blockIdx.x * blockDim.x + threadIdx.x;
    int grp = tid >> 3;
    int q   = tid & 7;
    if (grp >= n_cand) return;
    const int4* Xv = (const int4*)(X + (size_t)grp * SET_SIZE);
    int4 x0 = Xv[0]; int4 x1 = Xv[1];
    int he = h[grp];
    int idx[SET_SIZE] = {x0.x, x0.y, x0.z, x0.w, x1.x, x1.y, x1.z, x1.w};
    float4 va[9], vb[9];
#pragma unroll
    for (int r = 0; r < SET_SIZE; ++r) {
        const float4* p = (const float4*)(node_emb + (size_t)idx[r] * EMB_DIM) + 2 * q;
        va[r] = p[0]; vb[r] = p[1];
    }
    {
        const float4* p = (const float4*)(hyperedge_emb + (size_t)he * EMB_DIM) + 2 * q;
        va[8] = p[0]; vb[8] = p[1];
    }
    float acc[NDOT];
#pragma unroll
    for (int s = 0; s < SET_SIZE; ++s)
        acc[s] = dot4f(va[8], va[s]) + dot4f(vb[8], vb[s]);
    {
        int k = SET_SIZE;
#pragma unroll
        for (int s = 0; s < SET_SIZE; ++s)
#pragma unroll
            for (int t = s; t < SET_SIZE; ++t, ++k)
                acc[k] = dot4f(va[s], va[t]) + dot4f(vb[s], vb[t]);
    }
#pragma unroll
    for (int i = 0; i < NDOT; ++i) {
        float x = acc[i];
        x += __shfl_xor(x, 1);
        x += __shfl_xor(x, 2);
        x += __shfl_xor(x, 4);
        acc[i] = x;
    }
    float smin = acc[0];
#pragma unroll
    for (int s = 1; s < SET_SIZE; ++s) smin = fminf(smin, acc[s]);
    float pmin = acc[SET_SIZE];
#pragma unroll
    for (int i = 1; i < NPAIR; ++i) pmin = fminf(pmin, acc[SET_SIZE + i]);
    float res = (q == 0) ? 1.0f / (1.0f + __expf(-smin))
                         : 1.0f / (1.0f + __expf(-pmin));
    if (q < 2) out[(size_t)grp * 2 + q] = res;
}

extern "C" void kernel_launch(void* const* d_in, const int* in_sizes, int n_in,
                              void* d_out, int out_size, void* d_ws, size_t ws_size,
                              hipStream_t stream) {
    const float* node_emb      = (const float*)d_in[0];
    const float* hyperedge_emb = (const float*)d_in[1];
    const int*   h             = (const int*)d_in[2];
    const int*   X             = (const int*)d_in[3];
    float*       out           = (float*)d_out;

    int n_node_elems = in_sizes[0];  // 6,400,000
    int n_he_elems   = in_sizes[1];  // 3,200,000
    int n_cand       = in_sizes[2];  // 200,000

    size_t need = ((size_t)n_node_elems + (size_t)n_he_elems) * sizeof(__half);
    int block = 256;
    long long total_threads = (long long)n_cand * 8;
    int grid_main = (int)((total_threads + block - 1) / block);

    if (ws_size >= need) {
        __half* node_f16 = (__half*)d_ws;
        __half* he_f16   = node_f16 + n_node_elems;

        int n8_node = n_node_elems / 8;
        int n8_he   = n_he_elems / 8;
        cvt_f32_f16_kernel<<<(n8_node + block - 1) / block, block, 0, stream>>>(
            node_emb, node_f16, n8_node);
        cvt_f32_f16_kernel<<<(n8_he + block - 1) / block, block, 0, stream>>>(
            hyperedge_emb, he_f16, n8_he);

        hyperedge_score_f16<<<grid_main, block, 0, stream>>>(
            node_f16, he_f16, h, X, out, n_cand);
    } else {
        hyperedge_score_f32<<<grid_main, block, 0, stream>>>(
            node_emb, hyperedge_emb, h, X, out, n_cand);
    }
}

// Round 4
// 114.737 us; speedup vs baseline: 4.3201x; 1.0944x over previous
//
#include <hip/hip_runtime.h>
#include <hip/hip_fp16.h>
#include <math.h>

#define SET_SIZE 8
#define EMB_DIM 64
#define NPAIR 36  // upper triangle incl diagonal of 8x8
#define NDOT (SET_SIZE + NPAIR)

typedef _Float16 f16x2 __attribute__((ext_vector_type(2)));

union Frag32 {
    float4 f4[2];   // two 16B raw loads (32B = 16 fp16)
    f16x2  h2[8];   // 16 fp16 elements
};

__device__ __forceinline__ float dot16_f16(const Frag32& a, const Frag32& b, float c) {
#pragma unroll
    for (int j = 0; j < 8; ++j)
        c = __builtin_amdgcn_fdot2(a.h2[j], b.h2[j], c, false);
    return c;
}

// Sum across the 4 lanes of a quad using DPP quad_perm (pure VALU, no LDS pipe).
// quad_perm [1,0,3,2] = 0xB1 (xor 1), quad_perm [2,3,0,1] = 0x4E (xor 2).
__device__ __forceinline__ float quad_reduce_add(float x) {
    int t = __builtin_amdgcn_update_dpp(0, __float_as_int(x), 0xB1, 0xF, 0xF, true);
    x += __int_as_float(t);
    t = __builtin_amdgcn_update_dpp(0, __float_as_int(x), 0x4E, 0xF, 0xF, true);
    x += __int_as_float(t);
    return x;
}

// Fused f32 -> f16 conversion for both tables; 8 floats per thread.
__global__ __launch_bounds__(256) void cvt_both_kernel(
    const float* __restrict__ a, const float* __restrict__ b,
    __half* __restrict__ oa, __half* __restrict__ ob, int n8a, int n8b)
{
    int i = blockIdx.x * blockDim.x + threadIdx.x;
    const float* in;
    __half* out;
    int j;
    if (i < n8a) { in = a; out = oa; j = i; }
    else if (i < n8a + n8b) { in = b; out = ob; j = i - n8a; }
    else return;
    const float4* p = (const float4*)in + 2 * (size_t)j;
    float4 x = p[0], y = p[1];
    union { __half2 h2[4]; float4 f4; } u;
    u.h2[0] = __floats2half2_rn(x.x, x.y);
    u.h2[1] = __floats2half2_rn(x.z, x.w);
    u.h2[2] = __floats2half2_rn(y.x, y.y);
    u.h2[3] = __floats2half2_rn(y.z, y.w);
    ((float4*)out)[j] = u.f4;
}

// 4 lanes per candidate. Lane q owns bytes [16q,16q+16) and [64+16q, 64+16q+16)
// of each 128B fp16 row -> each load instruction covers a contiguous fully-used
// 64B segment per quad. 44 dots accumulate per-lane in f32 (v_dot2_f32_f16),
// then 2 DPP quad_perm steps finish each dot with zero LDS-pipe traffic.
__global__ __launch_bounds__(256, 3) void hyperedge_score_q4(
    const __half* __restrict__ node_f16,   // [N_NODES, 64]
    const __half* __restrict__ he_f16,     // [N_HYPEREDGES, 64]
    const int*    __restrict__ h,          // [E]
    const int*    __restrict__ X,          // [E, 8]
    float*        __restrict__ out,        // [E, 2]
    int n_cand)
{
    int tid = blockIdx.x * blockDim.x + threadIdx.x;
    int grp = tid >> 2;   // candidate id
    int q   = tid & 3;    // lane within quad
    if (grp >= n_cand) return;

    const int4* Xv = (const int4*)(X + (size_t)grp * SET_SIZE);
    int4 x0 = Xv[0];
    int4 x1 = Xv[1];
    int he = h[grp];
    int idx[SET_SIZE] = {x0.x, x0.y, x0.z, x0.w, x1.x, x1.y, x1.z, x1.w};

    Frag32 v[9];
#pragma unroll
    for (int r = 0; r < SET_SIZE; ++r) {
        const float4* p = (const float4*)(node_f16 + (size_t)idx[r] * EMB_DIM);
        v[r].f4[0] = p[q];
        v[r].f4[1] = p[q + 4];
    }
    {
        const float4* p = (const float4*)(he_f16 + (size_t)he * EMB_DIM);
        v[8].f4[0] = p[q];
        v[8].f4[1] = p[q + 4];
    }

    float acc[NDOT];
#pragma unroll
    for (int s = 0; s < SET_SIZE; ++s)
        acc[s] = dot16_f16(v[8], v[s], 0.0f);
    {
        int k = SET_SIZE;
#pragma unroll
        for (int s = 0; s < SET_SIZE; ++s) {
#pragma unroll
            for (int t = s; t < SET_SIZE; ++t, ++k)
                acc[k] = dot16_f16(v[s], v[t], 0.0f);
        }
    }

#pragma unroll
    for (int i = 0; i < NDOT; ++i)
        acc[i] = quad_reduce_add(acc[i]);

    // sigmoid is monotonic: min(sigmoid(x)) == sigmoid(min(x))
    float smin = acc[0];
#pragma unroll
    for (int s = 1; s < SET_SIZE; ++s) smin = fminf(smin, acc[s]);
    float pmin = acc[SET_SIZE];
#pragma unroll
    for (int i = 1; i < NPAIR; ++i) pmin = fminf(pmin, acc[SET_SIZE + i]);

    float res = (q == 0) ? 1.0f / (1.0f + __expf(-smin))
                         : 1.0f / (1.0f + __expf(-pmin));
    if (q < 2) out[(size_t)grp * 2 + q] = res;
}

// ---- f32 fallback (R2 structure) if workspace is too small ----
__device__ __forceinline__ float dot4f(float4 a, float4 b) {
    return fmaf(a.x, b.x, fmaf(a.y, b.y, fmaf(a.z, b.z, a.w * b.w)));
}

__global__ __launch_bounds__(256) void hyperedge_score_f32(
    const float* __restrict__ node_emb, const float* __restrict__ hyperedge_emb,
    const int* __restrict__ h, const int* __restrict__ X,
    float* __restrict__ out, int n_cand)
{
    int tid = blockIdx.x * blockDim.x + threadIdx.x;
    int grp = tid >> 3;
    int q   = tid & 7;
    if (grp >= n_cand) return;
    const int4* Xv = (const int4*)(X + (size_t)grp * SET_SIZE);
    int4 x0 = Xv[0]; int4 x1 = Xv[1];
    int he = h[grp];
    int idx[SET_SIZE] = {x0.x, x0.y, x0.z, x0.w, x1.x, x1.y, x1.z, x1.w};
    float4 va[9], vb[9];
#pragma unroll
    for (int r = 0; r < SET_SIZE; ++r) {
        const float4* p = (const float4*)(node_emb + (size_t)idx[r] * EMB_DIM) + 2 * q;
        va[r] = p[0]; vb[r] = p[1];
    }
    {
        const float4* p = (const float4*)(hyperedge_emb + (size_t)he * EMB_DIM) + 2 * q;
        va[8] = p[0]; vb[8] = p[1];
    }
    float acc[NDOT];
#pragma unroll
    for (int s = 0; s < SET_SIZE; ++s)
        acc[s] = dot4f(va[8], va[s]) + dot4f(vb[8], vb[s]);
    {
        int k = SET_SIZE;
#pragma unroll
        for (int s = 0; s < SET_SIZE; ++s)
#pragma unroll
            for (int t = s; t < SET_SIZE; ++t, ++k)
                acc[k] = dot4f(va[s], va[t]) + dot4f(vb[s], vb[t]);
    }
#pragma unroll
    for (int i = 0; i < NDOT; ++i) {
        float x = acc[i];
        x += __shfl_xor(x, 1);
        x += __shfl_xor(x, 2);
        x += __shfl_xor(x, 4);
        acc[i] = x;
    }
    float smin = acc[0];
#pragma unroll
    for (int s = 1; s < SET_SIZE; ++s) smin = fminf(smin, acc[s]);
    float pmin = acc[SET_SIZE];
#pragma unroll
    for (int i = 1; i < NPAIR; ++i) pmin = fminf(pmin, acc[SET_SIZE + i]);
    float res = (q == 0) ? 1.0f / (1.0f + __expf(-smin))
                         : 1.0f / (1.0f + __expf(-pmin));
    if (q < 2) out[(size_t)grp * 2 + q] = res;
}

extern "C" void kernel_launch(void* const* d_in, const int* in_sizes, int n_in,
                              void* d_out, int out_size, void* d_ws, size_t ws_size,
                              hipStream_t stream) {
    const float* node_emb      = (const float*)d_in[0];
    const float* hyperedge_emb = (const float*)d_in[1];
    const int*   h             = (const int*)d_in[2];
    const int*   X             = (const int*)d_in[3];
    float*       out           = (float*)d_out;

    int n_node_elems = in_sizes[0];  // 6,400,000
    int n_he_elems   = in_sizes[1];  // 3,200,000
    int n_cand       = in_sizes[2];  // 200,000

    size_t need = ((size_t)n_node_elems + (size_t)n_he_elems) * sizeof(__half);
    int block = 256;

    if (ws_size >= need) {
        __half* node_f16 = (__half*)d_ws;
        __half* he_f16   = node_f16 + n_node_elems;

        int n8_node = n_node_elems / 8;
        int n8_he   = n_he_elems / 8;
        int n8_tot  = n8_node + n8_he;
        cvt_both_kernel<<<(n8_tot + block - 1) / block, block, 0, stream>>>(
            node_emb, hyperedge_emb, node_f16, he_f16, n8_node, n8_he);

        long long total_threads = (long long)n_cand * 4;
        int grid_main = (int)((total_threads + block - 1) / block);
        hyperedge_score_q4<<<grid_main, block, 0, stream>>>(
            node_f16, he_f16, h, X, out, n_cand);
    } else {
        long long total_threads = (long long)n_cand * 8;
        int grid_main = (int)((total_threads + block - 1) / block);
        hyperedge_score_f32<<<grid_main, block, 0, stream>>>(
            node_emb, hyperedge_emb, h, X, out, n_cand);
    }
}

// Round 5
// 114.368 us; speedup vs baseline: 4.3340x; 1.0032x over previous
//
#include <hip/hip_runtime.h>
#include <hip/hip_fp16.h>
#include <math.h>
#include <float.h>

#define SET_SIZE 8
#define EMB_DIM 64
#define NPAIR 36  // upper triangle incl diagonal of 8x8
#define NDOT (SET_SIZE + NPAIR)

typedef _Float16 f16x2 __attribute__((ext_vector_type(2)));

union Frag32 {
    float4 f4[2];   // two 16B raw loads (32B = 16 fp16)
    f16x2  h2[8];   // 16 fp16 elements
};

__device__ __forceinline__ float dot16_f16(const Frag32& a, const Frag32& b) {
    float c = 0.0f;
#pragma unroll
    for (int j = 0; j < 8; ++j)
        c = __builtin_amdgcn_fdot2(a.h2[j], b.h2[j], c, false);
    return c;
}

// Sum across the 4 lanes of a quad using DPP quad_perm (pure VALU, no LDS pipe).
// quad_perm [1,0,3,2] = 0xB1 (xor 1), quad_perm [2,3,0,1] = 0x4E (xor 2).
__device__ __forceinline__ float quad_reduce_add(float x) {
    int t = __builtin_amdgcn_update_dpp(0, __float_as_int(x), 0xB1, 0xF, 0xF, true);
    x += __int_as_float(t);
    t = __builtin_amdgcn_update_dpp(0, __float_as_int(x), 0x4E, 0xF, 0xF, true);
    x += __int_as_float(t);
    return x;
}

// Fused f32 -> f16 conversion for both tables; 8 floats per thread.
__global__ __launch_bounds__(256) void cvt_both_kernel(
    const float* __restrict__ a, const float* __restrict__ b,
    __half* __restrict__ oa, __half* __restrict__ ob, int n8a, int n8b)
{
    int i = blockIdx.x * blockDim.x + threadIdx.x;
    const float* in;
    __half* out;
    int j;
    if (i < n8a) { in = a; out = oa; j = i; }
    else if (i < n8a + n8b) { in = b; out = ob; j = i - n8a; }
    else return;
    const float4* p = (const float4*)in + 2 * (size_t)j;
    float4 x = p[0], y = p[1];
    union { __half2 h2[4]; float4 f4; } u;
    u.h2[0] = __floats2half2_rn(x.x, x.y);
    u.h2[1] = __floats2half2_rn(x.z, x.w);
    u.h2[2] = __floats2half2_rn(y.x, y.y);
    u.h2[3] = __floats2half2_rn(y.z, y.w);
    ((float4*)out)[j] = u.f4;
}

// 4 lanes per candidate; lane q owns 32B of each 128B fp16 row. Each dot is
// computed, quad-reduced via DPP, and folded into the running min IMMEDIATELY,
// so liveness is just the 9 row fragments (72 VGPRs) + 2 running mins.
// __launch_bounds__(256,5) forces the allocator to keep it that way
// (<=~102 VGPRs -> 5 waves/SIMD) for latency hiding on the random gathers.
__global__ __launch_bounds__(256, 5) void hyperedge_score_q4(
    const __half* __restrict__ node_f16,   // [N_NODES, 64]
    const __half* __restrict__ he_f16,     // [N_HYPEREDGES, 64]
    const int*    __restrict__ h,          // [E]
    const int*    __restrict__ X,          // [E, 8]
    float*        __restrict__ out,        // [E, 2]
    int n_cand)
{
    int tid = blockIdx.x * blockDim.x + threadIdx.x;
    int grp = tid >> 2;   // candidate id
    int q   = tid & 3;    // lane within quad
    if (grp >= n_cand) return;

    const int4* Xv = (const int4*)(X + (size_t)grp * SET_SIZE);
    int4 x0 = Xv[0];
    int4 x1 = Xv[1];
    int he = h[grp];
    int idx[SET_SIZE] = {x0.x, x0.y, x0.z, x0.w, x1.x, x1.y, x1.z, x1.w};

    Frag32 v[9];
#pragma unroll
    for (int r = 0; r < SET_SIZE; ++r) {
        const float4* p = (const float4*)(node_f16 + (size_t)idx[r] * EMB_DIM);
        v[r].f4[0] = p[q];
        v[r].f4[1] = p[q + 4];
    }
    {
        const float4* p = (const float4*)(he_f16 + (size_t)he * EMB_DIM);
        v[8].f4[0] = p[q];
        v[8].f4[1] = p[q + 4];
    }

    // Star dots: immediate reduce + min-fold.
    float smin = FLT_MAX;
#pragma unroll
    for (int s = 0; s < SET_SIZE; ++s) {
        float d = quad_reduce_add(dot16_f16(v[8], v[s]));
        smin = fminf(smin, d);
    }

    // Pair dots (upper triangle incl diagonal): immediate reduce + min-fold.
    float pmin = FLT_MAX;
#pragma unroll
    for (int s = 0; s < SET_SIZE; ++s) {
#pragma unroll
        for (int t = s; t < SET_SIZE; ++t) {
            float d = quad_reduce_add(dot16_f16(v[s], v[t]));
            pmin = fminf(pmin, d);
        }
    }

    // sigmoid is monotonic: min(sigmoid(x)) == sigmoid(min(x))
    float res = (q == 0) ? 1.0f / (1.0f + __expf(-smin))
                         : 1.0f / (1.0f + __expf(-pmin));
    if (q < 2) out[(size_t)grp * 2 + q] = res;
}

// ---- f32 fallback (R2 structure) if workspace is too small ----
__device__ __forceinline__ float dot4f(float4 a, float4 b) {
    return fmaf(a.x, b.x, fmaf(a.y, b.y, fmaf(a.z, b.z, a.w * b.w)));
}

__global__ __launch_bounds__(256) void hyperedge_score_f32(
    const float* __restrict__ node_emb, const float* __restrict__ hyperedge_emb,
    const int* __restrict__ h, const int* __restrict__ X,
    float* __restrict__ out, int n_cand)
{
    int tid = blockIdx.x * blockDim.x + threadIdx.x;
    int grp = tid >> 3;
    int q   = tid & 7;
    if (grp >= n_cand) return;
    const int4* Xv = (const int4*)(X + (size_t)grp * SET_SIZE);
    int4 x0 = Xv[0]; int4 x1 = Xv[1];
    int he = h[grp];
    int idx[SET_SIZE] = {x0.x, x0.y, x0.z, x0.w, x1.x, x1.y, x1.z, x1.w};
    float4 va[9], vb[9];
#pragma unroll
    for (int r = 0; r < SET_SIZE; ++r) {
        const float4* p = (const float4*)(node_emb + (size_t)idx[r] * EMB_DIM) + 2 * q;
        va[r] = p[0]; vb[r] = p[1];
    }
    {
        const float4* p = (const float4*)(hyperedge_emb + (size_t)he * EMB_DIM) + 2 * q;
        va[8] = p[0]; vb[8] = p[1];
    }
    float acc[NDOT];
#pragma unroll
    for (int s = 0; s < SET_SIZE; ++s)
        acc[s] = dot4f(va[8], va[s]) + dot4f(vb[8], vb[s]);
    {
        int k = SET_SIZE;
#pragma unroll
        for (int s = 0; s < SET_SIZE; ++s)
#pragma unroll
            for (int t = s; t < SET_SIZE; ++t, ++k)
                acc[k] = dot4f(va[s], va[t]) + dot4f(vb[s], vb[t]);
    }
#pragma unroll
    for (int i = 0; i < NDOT; ++i) {
        float x = acc[i];
        x += __shfl_xor(x, 1);
        x += __shfl_xor(x, 2);
        x += __shfl_xor(x, 4);
        acc[i] = x;
    }
    float smin = acc[0];
#pragma unroll
    for (int s = 1; s < SET_SIZE; ++s) smin = fminf(smin, acc[s]);
    float pmin = acc[SET_SIZE];
#pragma unroll
    for (int i = 1; i < NPAIR; ++i) pmin = fminf(pmin, acc[SET_SIZE + i]);
    float res = (q == 0) ? 1.0f / (1.0f + __expf(-smin))
                         : 1.0f / (1.0f + __expf(-pmin));
    if (q < 2) out[(size_t)grp * 2 + q] = res;
}

extern "C" void kernel_launch(void* const* d_in, const int* in_sizes, int n_in,
                              void* d_out, int out_size, void* d_ws, size_t ws_size,
                              hipStream_t stream) {
    const float* node_emb      = (const float*)d_in[0];
    const float* hyperedge_emb = (const float*)d_in[1];
    const int*   h             = (const int*)d_in[2];
    const int*   X             = (const int*)d_in[3];
    float*       out           = (float*)d_out;

    int n_node_elems = in_sizes[0];  // 6,400,000
    int n_he_elems   = in_sizes[1];  // 3,200,000
    int n_cand       = in_sizes[2];  // 200,000

    size_t need = ((size_t)n_node_elems + (size_t)n_he_elems) * sizeof(__half);
    int block = 256;

    if (ws_size >= need) {
        __half* node_f16 = (__half*)d_ws;
        __half* he_f16   = node_f16 + n_node_elems;

        int n8_node = n_node_elems / 8;
        int n8_he   = n_he_elems / 8;
        int n8_tot  = n8_node + n8_he;
        cvt_both_kernel<<<(n8_tot + block - 1) / block, block, 0, stream>>>(
            node_emb, hyperedge_emb, node_f16, he_f16, n8_node, n8_he);

        long long total_threads = (long long)n_cand * 4;
        int grid_main = (int)((total_threads + block - 1) / block);
        hyperedge_score_q4<<<grid_main, block, 0, stream>>>(
            node_f16, he_f16, h, X, out, n_cand);
    } else {
        long long total_threads = (long long)n_cand * 8;
        int grid_main = (int)((total_threads + block - 1) / block);
        hyperedge_score_f32<<<grid_main, block, 0, stream>>>(
            node_emb, hyperedge_emb, h, X, out, n_cand);
    }
}